// Round 3
// baseline (1069.826 us; speedup 1.0000x reference)
//
#include <hip/hip_runtime.h>

// CostVolumeLayer: out[b, idx(i,j), y, x] = (1/81) * sum_c x1[b,c,y,x] * x2[b,c,y-i,x-j]
// i,j in [-4,4], idx = (9i+j) mod 81.  x1,x2: (8,192,128,256) fp32; out: (8,81,128,256) fp32.
//
// Banded MFMA (verified) + latency pipeline + XCD swizzle + LDS epilogue.
// Round 5: the kernel is LATENCY-starved, not BW-bound (420us vs 168us roofline,
// all pipes <10% busy, occupancy 22.6%). Bytes-in-flight/CU ~3KB vs ~22KB needed.
//  - __launch_bounds__(256,4): 4 blocks/CU (VGPR already exactly 128 = 4 waves/SIMD
//    cap; LDS 4x36.9KB = 147KB <= 160KB). Doubles outstanding bytes.
//  - epilogue stores via nontemporal: 64B half-line stores were write-allocating in
//    L2 and re-fetching (WRITE 562MB vs 85MB useful); nt streams them out.

#define SR     4
#define NDISP  81
#define CH     192
#define HH     128
#define WW     256
#define BB     8
#define TILE   16
#define REGN   24          // TILE + 2*SR
#define KC     32          // channels per chunk
#define NCHUNK 6           // 192/32
#define HWSZ   (HH * WW)   // 32768, fits int

typedef __attribute__((ext_vector_type(8))) short  short8;   // 8 bf16 = 4 VGPRs
typedef __attribute__((ext_vector_type(4))) float  float4v;

#if __has_builtin(__builtin_amdgcn_cvt_pk_bf16_f32)
typedef __attribute__((ext_vector_type(2))) __bf16 bf16x2;
__device__ __forceinline__ unsigned packbf(float a, float b) {
    union { bf16x2 v; unsigned u; } c;
    c.v = __builtin_amdgcn_cvt_pk_bf16_f32(a, b);   // lo=a, hi=b
    return c.u;
}
#else
__device__ __forceinline__ unsigned short f2bf(float f) {
    union { float f; unsigned u; } v; v.f = f;
    unsigned r = v.u + 0x7FFFu + ((v.u >> 16) & 1u);
    return (unsigned short)(r >> 16);
}
__device__ __forceinline__ unsigned packbf(float a, float b) {
    return (unsigned)f2bf(a) | ((unsigned)f2bf(b) << 16);
}
#endif

// LDS: per halo pixel p one 64B row (32ch bf16 as 16 dwords); 16B block column
// XOR-swizzled by (p>>1)&3. Pair cp lives in block cp>>2 at dword cp&3.
__device__ __forceinline__ int lds_addr(int p, int cp) {
    return (p << 6) + ((((cp >> 2) ^ ((p >> 1) & 3)) << 4) | ((cp & 3) << 2));
}

__global__ __launch_bounds__(256, 4)
void costvol_kernel(const float* __restrict__ x1, const float* __restrict__ x2,
                    float* __restrict__ out) {
    __shared__ __align__(16) char s_x2[REGN * REGN * KC * 2];   // 36864 B

    const int tid = threadIdx.x;

    // ---- XCD-aware bijective swizzle: flat dispatch id -> spatial tile id ----
    // 1024 blocks, 8 XCDs, 128 blocks/XCD = one full batch image per XCD,
    // row-major tile order (x fastest) for halo L2 reuse.
    const int flat = blockIdx.x + (blockIdx.y << 4) + (blockIdx.z << 7);
    const int swz  = ((flat & 7) << 7) + (flat >> 3);
    const int x0 = (swz & 15) * TILE;
    const int y0 = ((swz >> 4) & 7) * TILE;
    const int bz = swz >> 7;

    const int lane = tid & 63;
    const int wv   = tid >> 6;
    const int wy   = wv >> 1, wx = wv & 1;     // wave quadrant (8x8 px)
    const int quad = lane >> 4;                // k-group (8 ch) / C row group
    const int dy   = (lane & 15) >> 2;         // pixel row within 4x4 M-tile
    const int dx   = lane & 3;

    const float* x1b = x1 + (size_t)bz * CH * HWSZ;
    const float* x2b = x2 + (size_t)bz * CH * HWSZ;

    // ---- x2 staging metadata: 9 units/thread, unit u = tid + 256*s ----
    // decomposition (cp, ry, vx): cp = u/144, ry = (u%144)/6, vx = u%6
    int u_off[9];
    unsigned okmask = 0;
    #pragma unroll
    for (int s = 0; s < 9; ++s) {
        int u = tid + 256 * s;
        int cp = u / 144, rem = u - cp * 144;
        int ry = rem / 6,  vx = rem - ry * 6;
        int gy = y0 - SR + ry, gx = x0 - SR + 4 * vx;
        bool ok = ((unsigned)gy < (unsigned)HH) && ((unsigned)gx < (unsigned)(WW - 3));
        int gyc = min(max(gy, 0), HH - 1);
        int gxc = min(max(gx, 0), WW - 4);
        u_off[s] = 2 * cp * HWSZ + gyc * WW + gxc;   // element offset, chunk-relative
        okmask |= (unsigned)ok << s;
    }
    // x1 pixel offsets for the 4 A-fragments (lane-fixed)
    int pixoff[2][2];
    #pragma unroll
    for (int mty = 0; mty < 2; ++mty)
        #pragma unroll
        for (int mtx = 0; mtx < 2; ++mtx)
            pixoff[mty][mtx] = (y0 + wy * 8 + mty * 4 + dy) * WW
                             + (x0 + wx * 8 + mtx * 4 + dx);

    float4v acc[2][2][9];
    #pragma unroll
    for (int a = 0; a < 2; ++a)
        #pragma unroll
        for (int b = 0; b < 2; ++b)
            #pragma unroll
            for (int o = 0; o < 9; ++o)
                acc[a][b][o] = (float4v){0.f, 0.f, 0.f, 0.f};

    float4v x2A[9], x2B[9];      // in-flight x2 batch (72 VGPRs)
    float   x1s[2][2][8];        // in-flight x1 batch (32 VGPRs)
    short8  A[2][2];

    auto issue_x2 = [&](int ck) {
        const float* p2 = x2b + (size_t)(ck * KC) * HWSZ;
        #pragma unroll
        for (int s = 0; s < 9; ++s) {
            const float* q = p2 + u_off[s];
            x2A[s] = *(const float4v*)q;           // ch 2cp   (always-valid clamped addr)
            x2B[s] = *(const float4v*)(q + HWSZ);  // ch 2cp+1
        }
    };
    auto pack_x2 = [&]() {
        #pragma unroll
        for (int s = 0; s < 9; ++s) {
            int u = tid + 256 * s;
            int cp = u / 144, rem = u - cp * 144;
            int ry = rem / 6,  vx = rem - ry * 6;
            int p = ry * REGN + 4 * vx;
            bool ok = (okmask >> s) & 1u;
            #pragma unroll
            for (int k = 0; k < 4; ++k) {
                unsigned pk = packbf(x2A[s][k], x2B[s][k]);
                pk = ok ? pk : 0u;
                *(unsigned*)(s_x2 + lds_addr(p + k, cp)) = pk;
            }
        }
    };
    auto issue_x1 = [&](int ck) {
        const float* p1 = x1b + (size_t)(ck * KC + quad * 8) * HWSZ;
        #pragma unroll
        for (int mty = 0; mty < 2; ++mty)
            #pragma unroll
            for (int mtx = 0; mtx < 2; ++mtx)
                #pragma unroll
                for (int j = 0; j < 8; ++j)
                    x1s[mty][mtx][j] = p1[(size_t)j * HWSZ + pixoff[mty][mtx]];
    };
    auto build_A = [&]() {
        #pragma unroll
        for (int mty = 0; mty < 2; ++mty)
            #pragma unroll
            for (int mtx = 0; mtx < 2; ++mtx) {
                union { short8 s8; unsigned u4[4]; } af;
                #pragma unroll
                for (int t = 0; t < 4; ++t)
                    af.u4[t] = packbf(x1s[mty][mtx][2 * t], x1s[mty][mtx][2 * t + 1]);
                A[mty][mtx] = af.s8;
            }
    };

    // Prologue: both streams for chunk 0 in flight (x2 first -> counted waits).
    issue_x2(0);
    issue_x1(0);
    for (int ck = 0; ck < NCHUNK; ++ck) {
        // barrier 1: prev chunk's LDS reads already consumed (lgkm waits precede
        // each MFMA), so a bare s_barrier suffices — keeps global loads in flight.
        asm volatile("s_barrier" ::: "memory");
        pack_x2();               // waits x2(ck) only (counted: x1(ck) stays in flight)
        if (ck + 1 < NCHUNK) issue_x2(ck + 1);   // feed the pipe across barrier 2
        // barrier 2: LDS writes must be visible -> lgkmcnt(0), but NOT vmcnt.
        asm volatile("s_waitcnt lgkmcnt(0)\n\ts_barrier" ::: "memory");
        build_A();               // waits x1(ck) — issued a full chunk ago: no stall
        if (ck + 1 < NCHUNK) issue_x1(ck + 1);   // full-chunk prefetch distance
        #pragma unroll
        for (int gy = 0; gy < 4; ++gy) {
            #pragma unroll
            for (int gx = 0; gx < 4; ++gx) {
                int p2 = (wy * 8 + gy * 4 + dy) * REGN + (wx * 8 + gx * 4 + dx);
                short8 Bf = *(const short8*)(s_x2 + (p2 << 6)
                              + ((quad ^ ((p2 >> 1) & 3)) << 4));
                #pragma unroll
                for (int mty = 0; mty < 2; ++mty) {
                    const int oyi = gy - mty;
                    if (oyi < 0 || oyi > 2) continue;
                    #pragma unroll
                    for (int mtx = 0; mtx < 2; ++mtx) {
                        const int oxi = gx - mtx;
                        if (oxi < 0 || oxi > 2) continue;
                        acc[mty][mtx][oyi * 3 + oxi] =
                            __builtin_amdgcn_mfma_f32_16x16x32_bf16(
                                A[mty][mtx], Bf, acc[mty][mtx][oyi * 3 + oxi], 0, 0, 0);
                    }
                }
            }
        }
    }

    // ---- epilogue: band extraction (round-1 math) -> LDS slices -> coalesced writes
    // 81 = 3 slices x 27 idx channels; slice buffer = 27*16*16*4 = 27648 B in s_x2.
    const float scale = 1.0f / 81.0f;
    const int nq = (lane >> 2) & 3;
    const int nx = lane & 3;
    float* s_out = (float*)s_x2;
    for (int sl = 0; sl < 3; ++sl) {
        const int lo = 27 * sl;
        __syncthreads();         // prior LDS use (B-frags / prev slice reads) done
        #pragma unroll
        for (int mty = 0; mty < 2; ++mty) {
            #pragma unroll
            for (int mtx = 0; mtx < 2; ++mtx) {
                const int oyl = wy * 8 + mty * 4 + quad;    // row within tile
                const int oxb = wx * 8 + mtx * 4;           // col base within tile
                #pragma unroll
                for (int oyi = 0; oyi < 3; ++oyi) {
                    const int ip = quad - nq - 4 * (oyi - 1);
                    if ((unsigned)(ip + SR) > 8u) continue;
                    #pragma unroll
                    for (int oxi = 0; oxi < 3; ++oxi) {
                        #pragma unroll
                        for (int reg = 0; reg < 4; ++reg) {
                            const int jp = reg - nx - 4 * (oxi - 1);
                            if ((unsigned)(jp + SR) > 8u) continue;
                            int idx = 9 * ip + jp;
                            if (idx < 0) idx += NDISP;
                            idx -= lo;
                            if ((unsigned)idx < 27u)
                                s_out[(idx << 8) + (oyl << 4) + oxb + reg] =
                                    acc[mty][mtx][oyi * 3 + oxi][reg] * scale;
                        }
                    }
                }
            }
        }
        __syncthreads();
        // cooperative full-line writes: 27*16 rows of 64B; 4 lanes per row.
        // nontemporal: no write-allocate (half-line stores were inflating
        // WRITE_SIZE to 562MB via partial-dirty evict + refetch).
        for (int k = tid; k < 27 * 64; k += 256) {
            const int idx_l = k >> 6;
            const int rem   = k & 63;
            const int row   = rem >> 2;
            const int c4    = rem & 3;
            float4v v = *(const float4v*)(s_out + 4 * k);
            __builtin_nontemporal_store(v,
                (float4v*)(out + ((size_t)(bz * NDISP + lo + idx_l) * HH + y0 + row) * WW
                           + x0 + (c4 << 2)));
        }
    }
}

extern "C" void kernel_launch(void* const* d_in, const int* in_sizes, int n_in,
                              void* d_out, int out_size, void* d_ws, size_t ws_size,
                              hipStream_t stream) {
    const float* x1 = (const float*)d_in[0];
    const float* x2 = (const float*)d_in[1];
    float* out = (float*)d_out;
    (void)in_sizes; (void)n_in; (void)out_size; (void)d_ws; (void)ws_size;

    dim3 grid(WW / TILE, HH / TILE, BB);   // (16, 8, 8) = 1024 blocks
    costvol_kernel<<<grid, 256, 0, stream>>>(x1, x2, out);
}

// Round 4
// 700.493 us; speedup vs baseline: 1.5272x; 1.5272x over previous
//
#include <hip/hip_runtime.h>

// CostVolumeLayer: out[b, idx(i,j), y, x] = (1/81) * sum_c x1[b,c,y,x] * x2[b,c,y-i,x-j]
// i,j in [-4,4], idx = (9i+j) mod 81.  x1,x2: (8,192,128,256) fp32; out: (8,81,128,256) fp32.
//
// Banded MFMA (verified) + latency pipeline + XCD swizzle + LDS epilogue.
// Round 6:
//  - REVERT launch_bounds to (256,2): round-3's (256,4) forced VGPR 128->64 and
//    spilled the 144-reg accumulator to scratch (+1.5GB traffic, 2x slower).
//  - LDS swizzle hash (p>>1)&3 -> (p>>2)&3: the old hash collapsed pack-side
//    ds_write banks to 2-4 (16-32-way conflict, 26-37M conflict cycles). New hash
//    varies across vx -> ~4-way. Read side re-derived: still covers all banks.
//  - Keep nontemporal epilogue stores (clean write-allocate test at 128 VGPR).

#define SR     4
#define NDISP  81
#define CH     192
#define HH     128
#define WW     256
#define BB     8
#define TILE   16
#define REGN   24          // TILE + 2*SR
#define KC     32          // channels per chunk
#define NCHUNK 6           // 192/32
#define HWSZ   (HH * WW)   // 32768, fits int

typedef __attribute__((ext_vector_type(8))) short  short8;   // 8 bf16 = 4 VGPRs
typedef __attribute__((ext_vector_type(4))) float  float4v;

#if __has_builtin(__builtin_amdgcn_cvt_pk_bf16_f32)
typedef __attribute__((ext_vector_type(2))) __bf16 bf16x2;
__device__ __forceinline__ unsigned packbf(float a, float b) {
    union { bf16x2 v; unsigned u; } c;
    c.v = __builtin_amdgcn_cvt_pk_bf16_f32(a, b);   // lo=a, hi=b
    return c.u;
}
#else
__device__ __forceinline__ unsigned short f2bf(float f) {
    union { float f; unsigned u; } v; v.f = f;
    unsigned r = v.u + 0x7FFFu + ((v.u >> 16) & 1u);
    return (unsigned short)(r >> 16);
}
__device__ __forceinline__ unsigned packbf(float a, float b) {
    return (unsigned)f2bf(a) | ((unsigned)f2bf(b) << 16);
}
#endif

// LDS: per halo pixel p one 64B row (32ch bf16 as 16 dwords); 16B block column
// XOR-swizzled by (p>>2)&3 (varies with vx across a staging wave AND with dy on
// the read side). Pair cp lives in block (cp>>2)^sw(p) at dword cp&3.
__device__ __forceinline__ int lds_addr(int p, int cp) {
    return (p << 6) + ((((cp >> 2) ^ ((p >> 2) & 3)) << 4) | ((cp & 3) << 2));
}

__global__ __launch_bounds__(256, 2)
void costvol_kernel(const float* __restrict__ x1, const float* __restrict__ x2,
                    float* __restrict__ out) {
    __shared__ __align__(16) char s_x2[REGN * REGN * KC * 2];   // 36864 B

    const int tid = threadIdx.x;

    // ---- XCD-aware bijective swizzle: flat dispatch id -> spatial tile id ----
    // 1024 blocks, 8 XCDs, 128 blocks/XCD = one full batch image per XCD,
    // row-major tile order (x fastest) for halo L2 reuse.
    const int flat = blockIdx.x + (blockIdx.y << 4) + (blockIdx.z << 7);
    const int swz  = ((flat & 7) << 7) + (flat >> 3);
    const int x0 = (swz & 15) * TILE;
    const int y0 = ((swz >> 4) & 7) * TILE;
    const int bz = swz >> 7;

    const int lane = tid & 63;
    const int wv   = tid >> 6;
    const int wy   = wv >> 1, wx = wv & 1;     // wave quadrant (8x8 px)
    const int quad = lane >> 4;                // k-group (8 ch) / C row group
    const int dy   = (lane & 15) >> 2;         // pixel row within 4x4 M-tile
    const int dx   = lane & 3;

    const float* x1b = x1 + (size_t)bz * CH * HWSZ;
    const float* x2b = x2 + (size_t)bz * CH * HWSZ;

    // ---- x2 staging metadata: 9 units/thread, unit u = tid + 256*s ----
    // decomposition (cp, ry, vx): cp = u/144, ry = (u%144)/6, vx = u%6
    int u_off[9];
    unsigned okmask = 0;
    #pragma unroll
    for (int s = 0; s < 9; ++s) {
        int u = tid + 256 * s;
        int cp = u / 144, rem = u - cp * 144;
        int ry = rem / 6,  vx = rem - ry * 6;
        int gy = y0 - SR + ry, gx = x0 - SR + 4 * vx;
        bool ok = ((unsigned)gy < (unsigned)HH) && ((unsigned)gx < (unsigned)(WW - 3));
        int gyc = min(max(gy, 0), HH - 1);
        int gxc = min(max(gx, 0), WW - 4);
        u_off[s] = 2 * cp * HWSZ + gyc * WW + gxc;   // element offset, chunk-relative
        okmask |= (unsigned)ok << s;
    }
    // x1 pixel offsets for the 4 A-fragments (lane-fixed)
    int pixoff[2][2];
    #pragma unroll
    for (int mty = 0; mty < 2; ++mty)
        #pragma unroll
        for (int mtx = 0; mtx < 2; ++mtx)
            pixoff[mty][mtx] = (y0 + wy * 8 + mty * 4 + dy) * WW
                             + (x0 + wx * 8 + mtx * 4 + dx);

    float4v acc[2][2][9];
    #pragma unroll
    for (int a = 0; a < 2; ++a)
        #pragma unroll
        for (int b = 0; b < 2; ++b)
            #pragma unroll
            for (int o = 0; o < 9; ++o)
                acc[a][b][o] = (float4v){0.f, 0.f, 0.f, 0.f};

    float4v x2A[9], x2B[9];      // in-flight x2 batch (72 VGPRs)
    float   x1s[2][2][8];        // in-flight x1 batch (32 VGPRs)
    short8  A[2][2];

    auto issue_x2 = [&](int ck) {
        const float* p2 = x2b + (size_t)(ck * KC) * HWSZ;
        #pragma unroll
        for (int s = 0; s < 9; ++s) {
            const float* q = p2 + u_off[s];
            x2A[s] = *(const float4v*)q;           // ch 2cp   (always-valid clamped addr)
            x2B[s] = *(const float4v*)(q + HWSZ);  // ch 2cp+1
        }
    };
    auto pack_x2 = [&]() {
        #pragma unroll
        for (int s = 0; s < 9; ++s) {
            int u = tid + 256 * s;
            int cp = u / 144, rem = u - cp * 144;
            int ry = rem / 6,  vx = rem - ry * 6;
            int p = ry * REGN + 4 * vx;
            bool ok = (okmask >> s) & 1u;
            #pragma unroll
            for (int k = 0; k < 4; ++k) {
                unsigned pk = packbf(x2A[s][k], x2B[s][k]);
                pk = ok ? pk : 0u;
                *(unsigned*)(s_x2 + lds_addr(p + k, cp)) = pk;
            }
        }
    };
    auto issue_x1 = [&](int ck) {
        const float* p1 = x1b + (size_t)(ck * KC + quad * 8) * HWSZ;
        #pragma unroll
        for (int mty = 0; mty < 2; ++mty)
            #pragma unroll
            for (int mtx = 0; mtx < 2; ++mtx)
                #pragma unroll
                for (int j = 0; j < 8; ++j)
                    x1s[mty][mtx][j] = p1[(size_t)j * HWSZ + pixoff[mty][mtx]];
    };
    auto build_A = [&]() {
        #pragma unroll
        for (int mty = 0; mty < 2; ++mty)
            #pragma unroll
            for (int mtx = 0; mtx < 2; ++mtx) {
                union { short8 s8; unsigned u4[4]; } af;
                #pragma unroll
                for (int t = 0; t < 4; ++t)
                    af.u4[t] = packbf(x1s[mty][mtx][2 * t], x1s[mty][mtx][2 * t + 1]);
                A[mty][mtx] = af.s8;
            }
    };

    // Prologue: both streams for chunk 0 in flight (x2 first -> counted waits).
    issue_x2(0);
    issue_x1(0);
    for (int ck = 0; ck < NCHUNK; ++ck) {
        // barrier 1: prev chunk's LDS reads already consumed (lgkm waits precede
        // each MFMA), so a bare s_barrier suffices — keeps global loads in flight.
        asm volatile("s_barrier" ::: "memory");
        pack_x2();               // waits x2(ck) only (counted: x1(ck) stays in flight)
        if (ck + 1 < NCHUNK) issue_x2(ck + 1);   // feed the pipe across barrier 2
        // barrier 2: LDS writes must be visible -> lgkmcnt(0), but NOT vmcnt.
        asm volatile("s_waitcnt lgkmcnt(0)\n\ts_barrier" ::: "memory");
        build_A();               // waits x1(ck) — issued a full chunk ago: no stall
        if (ck + 1 < NCHUNK) issue_x1(ck + 1);   // full-chunk prefetch distance
        #pragma unroll
        for (int gy = 0; gy < 4; ++gy) {
            #pragma unroll
            for (int gx = 0; gx < 4; ++gx) {
                int p2 = (wy * 8 + gy * 4 + dy) * REGN + (wx * 8 + gx * 4 + dx);
                short8 Bf = *(const short8*)(s_x2 + (p2 << 6)
                              + ((quad ^ ((p2 >> 2) & 3)) << 4));
                #pragma unroll
                for (int mty = 0; mty < 2; ++mty) {
                    const int oyi = gy - mty;
                    if (oyi < 0 || oyi > 2) continue;
                    #pragma unroll
                    for (int mtx = 0; mtx < 2; ++mtx) {
                        const int oxi = gx - mtx;
                        if (oxi < 0 || oxi > 2) continue;
                        acc[mty][mtx][oyi * 3 + oxi] =
                            __builtin_amdgcn_mfma_f32_16x16x32_bf16(
                                A[mty][mtx], Bf, acc[mty][mtx][oyi * 3 + oxi], 0, 0, 0);
                    }
                }
            }
        }
    }

    // ---- epilogue: band extraction (round-1 math) -> LDS slices -> coalesced writes
    // 81 = 3 slices x 27 idx channels; slice buffer = 27*16*16*4 = 27648 B in s_x2.
    const float scale = 1.0f / 81.0f;
    const int nq = (lane >> 2) & 3;
    const int nx = lane & 3;
    float* s_out = (float*)s_x2;
    for (int sl = 0; sl < 3; ++sl) {
        const int lo = 27 * sl;
        __syncthreads();         // prior LDS use (B-frags / prev slice reads) done
        #pragma unroll
        for (int mty = 0; mty < 2; ++mty) {
            #pragma unroll
            for (int mtx = 0; mtx < 2; ++mtx) {
                const int oyl = wy * 8 + mty * 4 + quad;    // row within tile
                const int oxb = wx * 8 + mtx * 4;           // col base within tile
                #pragma unroll
                for (int oyi = 0; oyi < 3; ++oyi) {
                    const int ip = quad - nq - 4 * (oyi - 1);
                    if ((unsigned)(ip + SR) > 8u) continue;
                    #pragma unroll
                    for (int oxi = 0; oxi < 3; ++oxi) {
                        #pragma unroll
                        for (int reg = 0; reg < 4; ++reg) {
                            const int jp = reg - nx - 4 * (oxi - 1);
                            if ((unsigned)(jp + SR) > 8u) continue;
                            int idx = 9 * ip + jp;
                            if (idx < 0) idx += NDISP;
                            idx -= lo;
                            if ((unsigned)idx < 27u)
                                s_out[(idx << 8) + (oyl << 4) + oxb + reg] =
                                    acc[mty][mtx][oyi * 3 + oxi][reg] * scale;
                        }
                    }
                }
            }
        }
        __syncthreads();
        // cooperative full-line writes: 27*16 rows of 64B; 4 lanes per row.
        // nontemporal: no write-allocate / no L2 pollution for streamed output.
        for (int k = tid; k < 27 * 64; k += 256) {
            const int idx_l = k >> 6;
            const int rem   = k & 63;
            const int row   = rem >> 2;
            const int c4    = rem & 3;
            float4v v = *(const float4v*)(s_out + 4 * k);
            __builtin_nontemporal_store(v,
                (float4v*)(out + ((size_t)(bz * NDISP + lo + idx_l) * HH + y0 + row) * WW
                           + x0 + (c4 << 2)));
        }
    }
}

extern "C" void kernel_launch(void* const* d_in, const int* in_sizes, int n_in,
                              void* d_out, int out_size, void* d_ws, size_t ws_size,
                              hipStream_t stream) {
    const float* x1 = (const float*)d_in[0];
    const float* x2 = (const float*)d_in[1];
    float* out = (float*)d_out;
    (void)in_sizes; (void)n_in; (void)out_size; (void)d_ws; (void)ws_size;

    dim3 grid(WW / TILE, HH / TILE, BB);   // (16, 8, 8) = 1024 blocks
    costvol_kernel<<<grid, 256, 0, stream>>>(x1, x2, out);
}

// Round 5
// 696.970 us; speedup vs baseline: 1.5350x; 1.0051x over previous
//
#include <hip/hip_runtime.h>

// CostVolumeLayer: out[b, idx(i,j), y, x] = (1/81) * sum_c x1[b,c,y,x] * x2[b,c,y-i,x-j]
// i,j in [-4,4], idx = (9i+j) mod 81.  x1,x2: (8,192,128,256) fp32; out: (8,81,128,256) fp32.
//
// Banded MFMA (verified) + latency pipeline + XCD swizzle + LDS epilogue.
// Round 7: traffic changes (FETCH 780->430, WRITE 253->545) never moved dur
// (~428/420/430us) -> kernel is CONCURRENCY-limited, not BW-limited. The two
// barriers per chunk align all waves' vmcnt stalls (lockstep). Fix:
//  - DOUBLE-BUFFER the bf16 LDS tile (36864 -> 73728 B; 2 blocks/CU = 147KB ok)
//  - ONE barrier per chunk: pack(ck)->buf[ck&1]; issue_x2(ck+1); build_A(ck);
//    issue_x1(ck+1); lgkmcnt(0)+barrier; MFMA(ck). WAR safe: pack(ck) overwrites
//    what MFMA(ck-2) read, barrier of iter ck-1 is in between. Waves now slip by
//    up to a chunk, so one wave's vmcnt stall overlaps sisters' MFMA.
//  - keep: (256,2) [128 VGPR, no spill], XCD swizzle, nt epilogue stores,
//    (p>>2)&3 read-conflict-free hash.

#define SR     4
#define NDISP  81
#define CH     192
#define HH     128
#define WW     256
#define BB     8
#define TILE   16
#define REGN   24          // TILE + 2*SR
#define KC     32          // channels per chunk
#define NCHUNK 6           // 192/32
#define HWSZ   (HH * WW)   // 32768, fits int
#define BUFSZ  (REGN * REGN * KC * 2)   // 36864 B per buffer

typedef __attribute__((ext_vector_type(8))) short  short8;   // 8 bf16 = 4 VGPRs
typedef __attribute__((ext_vector_type(4))) float  float4v;

#if __has_builtin(__builtin_amdgcn_cvt_pk_bf16_f32)
typedef __attribute__((ext_vector_type(2))) __bf16 bf16x2;
__device__ __forceinline__ unsigned packbf(float a, float b) {
    union { bf16x2 v; unsigned u; } c;
    c.v = __builtin_amdgcn_cvt_pk_bf16_f32(a, b);   // lo=a, hi=b
    return c.u;
}
#else
__device__ __forceinline__ unsigned short f2bf(float f) {
    union { float f; unsigned u; } v; v.f = f;
    unsigned r = v.u + 0x7FFFu + ((v.u >> 16) & 1u);
    return (unsigned short)(r >> 16);
}
__device__ __forceinline__ unsigned packbf(float a, float b) {
    return (unsigned)f2bf(a) | ((unsigned)f2bf(b) << 16);
}
#endif

// LDS: per halo pixel p one 64B row (32ch bf16 as 16 dwords); 16B block column
// XOR-swizzled by (p>>2)&3. Pair cp lives in block (cp>>2)^sw at dword cp&3.
__device__ __forceinline__ int lds_addr(int p, int cp) {
    return (p << 6) + ((((cp >> 2) ^ ((p >> 2) & 3)) << 4) | ((cp & 3) << 2));
}

__global__ __launch_bounds__(256, 2)
void costvol_kernel(const float* __restrict__ x1, const float* __restrict__ x2,
                    float* __restrict__ out) {
    __shared__ __align__(16) char s_x2[2 * BUFSZ];   // 73728 B (double buffer)

    const int tid = threadIdx.x;

    // ---- XCD-aware bijective swizzle: flat dispatch id -> spatial tile id ----
    const int flat = blockIdx.x + (blockIdx.y << 4) + (blockIdx.z << 7);
    const int swz  = ((flat & 7) << 7) + (flat >> 3);
    const int x0 = (swz & 15) * TILE;
    const int y0 = ((swz >> 4) & 7) * TILE;
    const int bz = swz >> 7;

    const int lane = tid & 63;
    const int wv   = tid >> 6;
    const int wy   = wv >> 1, wx = wv & 1;     // wave quadrant (8x8 px)
    const int quad = lane >> 4;                // k-group (8 ch) / C row group
    const int dy   = (lane & 15) >> 2;         // pixel row within 4x4 M-tile
    const int dx   = lane & 3;

    const float* x1b = x1 + (size_t)bz * CH * HWSZ;
    const float* x2b = x2 + (size_t)bz * CH * HWSZ;

    // ---- x2 staging metadata: 9 units/thread, unit u = tid + 256*s ----
    int u_off[9];
    unsigned okmask = 0;
    #pragma unroll
    for (int s = 0; s < 9; ++s) {
        int u = tid + 256 * s;
        int cp = u / 144, rem = u - cp * 144;
        int ry = rem / 6,  vx = rem - ry * 6;
        int gy = y0 - SR + ry, gx = x0 - SR + 4 * vx;
        bool ok = ((unsigned)gy < (unsigned)HH) && ((unsigned)gx < (unsigned)(WW - 3));
        int gyc = min(max(gy, 0), HH - 1);
        int gxc = min(max(gx, 0), WW - 4);
        u_off[s] = 2 * cp * HWSZ + gyc * WW + gxc;   // element offset, chunk-relative
        okmask |= (unsigned)ok << s;
    }
    // x1 pixel offsets for the 4 A-fragments (lane-fixed)
    int pixoff[2][2];
    #pragma unroll
    for (int mty = 0; mty < 2; ++mty)
        #pragma unroll
        for (int mtx = 0; mtx < 2; ++mtx)
            pixoff[mty][mtx] = (y0 + wy * 8 + mty * 4 + dy) * WW
                             + (x0 + wx * 8 + mtx * 4 + dx);

    float4v acc[2][2][9];
    #pragma unroll
    for (int a = 0; a < 2; ++a)
        #pragma unroll
        for (int b = 0; b < 2; ++b)
            #pragma unroll
            for (int o = 0; o < 9; ++o)
                acc[a][b][o] = (float4v){0.f, 0.f, 0.f, 0.f};

    float4v x2A[9], x2B[9];      // in-flight x2 batch (72 VGPRs)
    float   x1s[2][2][8];        // in-flight x1 batch (32 VGPRs)
    short8  A[2][2];

    auto issue_x2 = [&](int ck) {
        const float* p2 = x2b + (size_t)(ck * KC) * HWSZ;
        #pragma unroll
        for (int s = 0; s < 9; ++s) {
            const float* q = p2 + u_off[s];
            x2A[s] = *(const float4v*)q;           // ch 2cp   (always-valid clamped addr)
            x2B[s] = *(const float4v*)(q + HWSZ);  // ch 2cp+1
        }
    };
    auto pack_x2 = [&](char* buf) {
        #pragma unroll
        for (int s = 0; s < 9; ++s) {
            int u = tid + 256 * s;
            int cp = u / 144, rem = u - cp * 144;
            int ry = rem / 6,  vx = rem - ry * 6;
            int p = ry * REGN + 4 * vx;
            bool ok = (okmask >> s) & 1u;
            #pragma unroll
            for (int k = 0; k < 4; ++k) {
                unsigned pk = packbf(x2A[s][k], x2B[s][k]);
                pk = ok ? pk : 0u;
                *(unsigned*)(buf + lds_addr(p + k, cp)) = pk;
            }
        }
    };
    auto issue_x1 = [&](int ck) {
        const float* p1 = x1b + (size_t)(ck * KC + quad * 8) * HWSZ;
        #pragma unroll
        for (int mty = 0; mty < 2; ++mty)
            #pragma unroll
            for (int mtx = 0; mtx < 2; ++mtx)
                #pragma unroll
                for (int j = 0; j < 8; ++j)
                    x1s[mty][mtx][j] = p1[(size_t)j * HWSZ + pixoff[mty][mtx]];
    };
    auto build_A = [&]() {
        #pragma unroll
        for (int mty = 0; mty < 2; ++mty)
            #pragma unroll
            for (int mtx = 0; mtx < 2; ++mtx) {
                union { short8 s8; unsigned u4[4]; } af;
                #pragma unroll
                for (int t = 0; t < 4; ++t)
                    af.u4[t] = packbf(x1s[mty][mtx][2 * t], x1s[mty][mtx][2 * t + 1]);
                A[mty][mtx] = af.s8;
            }
    };

    // Prologue: both streams for chunk 0 in flight (x2 first -> counted waits).
    issue_x2(0);
    issue_x1(0);
    for (int ck = 0; ck < NCHUNK; ++ck) {
        char* buf = s_x2 + (ck & 1) * BUFSZ;
        pack_x2(buf);            // waits x2(ck) only; sister waves may still be in MFMA(ck-1)
        if (ck + 1 < NCHUNK) issue_x2(ck + 1);
        build_A();               // waits x1(ck) — issued a full chunk ago
        if (ck + 1 < NCHUNK) issue_x1(ck + 1);
        // single barrier per chunk: my pack writes visible (lgkm0) and everyone
        // is past MFMA(ck-1) reads of the OTHER buffer. Global loads stay in flight.
        asm volatile("s_waitcnt lgkmcnt(0)\n\ts_barrier" ::: "memory");
        #pragma unroll
        for (int gy = 0; gy < 4; ++gy) {
            #pragma unroll
            for (int gx = 0; gx < 4; ++gx) {
                int p2 = (wy * 8 + gy * 4 + dy) * REGN + (wx * 8 + gx * 4 + dx);
                short8 Bf = *(const short8*)(buf + (p2 << 6)
                              + ((quad ^ ((p2 >> 2) & 3)) << 4));
                #pragma unroll
                for (int mty = 0; mty < 2; ++mty) {
                    const int oyi = gy - mty;
                    if (oyi < 0 || oyi > 2) continue;
                    #pragma unroll
                    for (int mtx = 0; mtx < 2; ++mtx) {
                        const int oxi = gx - mtx;
                        if (oxi < 0 || oxi > 2) continue;
                        acc[mty][mtx][oyi * 3 + oxi] =
                            __builtin_amdgcn_mfma_f32_16x16x32_bf16(
                                A[mty][mtx], Bf, acc[mty][mtx][oyi * 3 + oxi], 0, 0, 0);
                    }
                }
            }
        }
    }

    // ---- epilogue: band extraction -> LDS slices -> coalesced nt writes ----
    // 81 = 3 slices x 27 idx channels; slice buffer = 27*16*16*4 = 27648 B.
    const float scale = 1.0f / 81.0f;
    const int nq = (lane >> 2) & 3;
    const int nx = lane & 3;
    float* s_out = (float*)s_x2;
    for (int sl = 0; sl < 3; ++sl) {
        const int lo = 27 * sl;
        __syncthreads();         // prior LDS use (B-frag reads / prev slice) done
        #pragma unroll
        for (int mty = 0; mty < 2; ++mty) {
            #pragma unroll
            for (int mtx = 0; mtx < 2; ++mtx) {
                const int oyl = wy * 8 + mty * 4 + quad;    // row within tile
                const int oxb = wx * 8 + mtx * 4;           // col base within tile
                #pragma unroll
                for (int oyi = 0; oyi < 3; ++oyi) {
                    const int ip = quad - nq - 4 * (oyi - 1);
                    if ((unsigned)(ip + SR) > 8u) continue;
                    #pragma unroll
                    for (int oxi = 0; oxi < 3; ++oxi) {
                        #pragma unroll
                        for (int reg = 0; reg < 4; ++reg) {
                            const int jp = reg - nx - 4 * (oxi - 1);
                            if ((unsigned)(jp + SR) > 8u) continue;
                            int idx = 9 * ip + jp;
                            if (idx < 0) idx += NDISP;
                            idx -= lo;
                            if ((unsigned)idx < 27u)
                                s_out[(idx << 8) + (oyl << 4) + oxb + reg] =
                                    acc[mty][mtx][oyi * 3 + oxi][reg] * scale;
                        }
                    }
                }
            }
        }
        __syncthreads();
        // cooperative full-line nt writes: 27*16 rows of 64B; 4 lanes per row.
        for (int k = tid; k < 27 * 64; k += 256) {
            const int idx_l = k >> 6;
            const int rem   = k & 63;
            const int row   = rem >> 2;
            const int c4    = rem & 3;
            float4v v = *(const float4v*)(s_out + 4 * k);
            __builtin_nontemporal_store(v,
                (float4v*)(out + ((size_t)(bz * NDISP + lo + idx_l) * HH + y0 + row) * WW
                           + x0 + (c4 << 2)));
        }
    }
}

extern "C" void kernel_launch(void* const* d_in, const int* in_sizes, int n_in,
                              void* d_out, int out_size, void* d_ws, size_t ws_size,
                              hipStream_t stream) {
    const float* x1 = (const float*)d_in[0];
    const float* x2 = (const float*)d_in[1];
    float* out = (float*)d_out;
    (void)in_sizes; (void)n_in; (void)out_size; (void)d_ws; (void)ws_size;

    dim3 grid(WW / TILE, HH / TILE, BB);   // (16, 8, 8) = 1024 blocks
    costvol_kernel<<<grid, 256, 0, stream>>>(x1, x2, out);
}

// Round 6
// 523.155 us; speedup vs baseline: 2.0450x; 1.3322x over previous
//
#include <hip/hip_runtime.h>

// CostVolumeLayer: out[b, idx(i,j), y, x] = (1/81) * sum_c x1[b,c,y,x] * x2[b,c,y-i,x-j]
// i,j in [-4,4], idx = (9i+j) mod 81.  x1,x2: (8,192,128,256) fp32; out: (8,81,128,256) fp32.
//
// Round 8: rounds 0-5 proved the kernel is pinned at ~430us by REGISTER-capped
// memory concurrency (~704 B in flight per wave -> ~5.6KB/CU -> ~3 TB/s, exactly
// as measured; traffic and barrier structure never mattered). Fix: stage x2 fp32
// straight to LDS via global_load_lds (in-flight capacity = LDS buffer, not VGPRs).
//  - KC=16, fp32 halo tile 24x24x16 double-buffered (2x36864 B, 2 blocks/CU).
//  - no pack pass, no ds_writes: B-frags built in MFMA phase from LDS fp32
//    (layout [vx][c][y]: 8 ds_read_b32, 2-way banks = free) + cvt_pk.
//  - K=16 into the proven 16x16x32 MFMA: quads 2-3 contribute zeros (A zeroed
//    explicitly; MFMA util is 1.3%, the waste is free; no new intrinsic risk).
//  - OOB: DMA uses clamped (always-valid) addresses; per-pixel pmask zeroes
//    B-frags at build. x1 stays register-staged (quads 0-1, 8ch each).
//  - 1 barrier/chunk: s_waitcnt vmcnt(32) keeps chunk ck+1's 9 DMA + 32 x1 loads
//    in flight across the whole MFMA phase; fences pin issue order for the count.

#define SR     4
#define NDISP  81
#define CH     192
#define HH     128
#define WW     256
#define BB     8
#define TILE   16
#define REGN   24          // TILE + 2*SR
#define KC     16          // channels per chunk (fp32 in LDS)
#define NCHUNK 12          // 192/16
#define HWSZ   (HH * WW)   // 32768, fits int
#define BUFSZ  (REGN * REGN * KC * 4)   // 36864 B fp32 halo tile per chunk

typedef __attribute__((ext_vector_type(8))) short  short8;   // 8 bf16 = 4 VGPRs
typedef __attribute__((ext_vector_type(4))) float  float4v;

#if __has_builtin(__builtin_amdgcn_cvt_pk_bf16_f32)
typedef __attribute__((ext_vector_type(2))) __bf16 bf16x2;
__device__ __forceinline__ unsigned packbf(float a, float b) {
    union { bf16x2 v; unsigned u; } c;
    c.v = __builtin_amdgcn_cvt_pk_bf16_f32(a, b);   // lo=a, hi=b
    return c.u;
}
#else
__device__ __forceinline__ unsigned short f2bf(float f) {
    union { float f; unsigned u; } v; v.f = f;
    unsigned r = v.u + 0x7FFFu + ((v.u >> 16) & 1u);
    return (unsigned short)(r >> 16);
}
__device__ __forceinline__ unsigned packbf(float a, float b) {
    return (unsigned)f2bf(a) | ((unsigned)f2bf(b) << 16);
}
#endif

typedef __attribute__((address_space(1))) void gvoid;
typedef __attribute__((address_space(3))) void lvoid;
__device__ __forceinline__ void gl_lds16(const void* g, void* l) {
    // one 16B-per-lane direct global->LDS transfer; LDS dest = uniform base + lane*16
    __builtin_amdgcn_global_load_lds((gvoid*)g, (lvoid*)l, 16, 0, 0);
}

__global__ __launch_bounds__(256, 2)
void costvol_kernel(const float* __restrict__ x1, const float* __restrict__ x2,
                    float* __restrict__ out) {
    __shared__ __align__(16) char s_x2[2 * BUFSZ];   // 73728 B (fp32 double buffer)

    const int tid = threadIdx.x;

    // ---- XCD-aware bijective swizzle: flat dispatch id -> spatial tile id ----
    const int flat = blockIdx.x + (blockIdx.y << 4) + (blockIdx.z << 7);
    const int swz  = ((flat & 7) << 7) + (flat >> 3);
    const int x0 = (swz & 15) * TILE;
    const int y0 = ((swz >> 4) & 7) * TILE;
    const int bz = swz >> 7;

    const int lane = tid & 63;
    const int wv   = tid >> 6;
    const int wy   = wv >> 1, wx = wv & 1;     // wave quadrant (8x8 px)
    const int quad = lane >> 4;                // k-group; quads 0-1 carry K=16
    const int dy   = (lane & 15) >> 2;         // pixel row within 4x4 M-tile
    const int dx   = lane & 3;

    const float* x1b = x1 + (size_t)bz * CH * HWSZ;
    const float* x2b = x2 + (size_t)bz * CH * HWSZ;

    // ---- x2 DMA metadata: 9 units/thread; unit u = wv*576 + i*64 + lane ----
    // LDS layout (per buffer): offset(u)=u*16 with u = (vx*16 + c)*24 + y
    // -> addr(c,y,x) = (x>>2)*6144 + c*384 + y*16 + (x&3)*4
    int g_off[9];
    #pragma unroll
    for (int i = 0; i < 9; ++i) {
        int u  = wv * 576 + i * 64 + lane;
        int vx = u / 384;
        int c  = (u / 24) & 15;
        int ry = u % 24;
        int gy = y0 - SR + ry, gx = x0 - SR + 4 * vx;
        int gyc = min(max(gy, 0), HH - 1);      // clamp: always-valid 16B-aligned addr
        int gxc = min(max(gx, 0), WW - 4);      // (OOB pixels zeroed at frag build)
        g_off[i] = c * HWSZ + gyc * WW + gxc;
    }
    // per-pixel validity mask for the 16 (gy,gx) fragment positions
    unsigned pmask = 0;
    #pragma unroll
    for (int gy = 0; gy < 4; ++gy)
        #pragma unroll
        for (int gx = 0; gx < 4; ++gx) {
            int p2y = wy * 8 + gy * 4 + dy, p2x = wx * 8 + gx * 4 + dx;
            bool ok = ((unsigned)(y0 - SR + p2y) < (unsigned)HH) &&
                      ((unsigned)(x0 - SR + p2x) < (unsigned)WW);
            pmask |= (unsigned)ok << (gy * 4 + gx);
        }
    // x1 pixel offsets for the 4 A-fragments (lane-fixed)
    int pixoff[2][2];
    #pragma unroll
    for (int mty = 0; mty < 2; ++mty)
        #pragma unroll
        for (int mtx = 0; mtx < 2; ++mtx)
            pixoff[mty][mtx] = (y0 + wy * 8 + mty * 4 + dy) * WW
                             + (x0 + wx * 8 + mtx * 4 + dx);

    float4v acc[2][2][9];
    #pragma unroll
    for (int a = 0; a < 2; ++a)
        #pragma unroll
        for (int b = 0; b < 2; ++b)
            #pragma unroll
            for (int o = 0; o < 9; ++o)
                acc[a][b][o] = (float4v){0.f, 0.f, 0.f, 0.f};

    float  x1s[2][2][8];       // x1 in-flight batch (quads 0-1 meaningful)
    short8 A[2][2];

    auto issue_dma = [&](int ck, int bufsel) {
        const float* p2 = x2b + (size_t)(ck * KC) * HWSZ;
        char* lbase = s_x2 + bufsel * BUFSZ + wv * 9216;
        #pragma unroll
        for (int i = 0; i < 9; ++i)
            gl_lds16((const void*)(p2 + g_off[i]), (void*)(lbase + i * 1024));
    };
    auto issue_x1 = [&](int ck) {
        if (quad < 2) {
            const float* p1 = x1b + (size_t)(ck * KC + quad * 8) * HWSZ;
            #pragma unroll
            for (int mty = 0; mty < 2; ++mty)
                #pragma unroll
                for (int mtx = 0; mtx < 2; ++mtx)
                    #pragma unroll
                    for (int j = 0; j < 8; ++j)
                        x1s[mty][mtx][j] = p1[(size_t)j * HWSZ + pixoff[mty][mtx]];
        }
    };
    auto build_A = [&]() {
        #pragma unroll
        for (int mty = 0; mty < 2; ++mty)
            #pragma unroll
            for (int mtx = 0; mtx < 2; ++mtx) {
                union { short8 s8; unsigned u4[4]; } af;
                #pragma unroll
                for (int t = 0; t < 4; ++t)
                    af.u4[t] = (quad < 2)
                        ? packbf(x1s[mty][mtx][2 * t], x1s[mty][mtx][2 * t + 1])
                        : 0u;   // quads 2-3 must be ZERO (garbage*0 would NaN)
                A[mty][mtx] = af.s8;
            }
    };

    // Prologue: chunk 0's DMA + x1 in flight (order matters for vmcnt counting).
    issue_dma(0, 0);
    asm volatile("" ::: "memory");
    issue_x1(0);
    asm volatile("" ::: "memory");

    for (int ck = 0; ck < NCHUNK; ++ck) {
        // vmcnt(32): retire the 9 DMA ops of chunk ck (the 32 x1 loads of ck may
        // stay in flight). Barrier: everyone's DMA(ck) landed AND everyone is
        // past MFMA(ck-1) -> safe to read buf[ck&1] and to overwrite the other.
        asm volatile("s_waitcnt vmcnt(32)\n\ts_barrier" ::: "memory");
        if (ck + 1 < NCHUNK) issue_dma(ck + 1, (ck + 1) & 1);
        asm volatile("" ::: "memory");
        build_A();                             // consumes x1s(ck) (auto vmcnt)
        if (ck + 1 < NCHUNK) issue_x1(ck + 1); // overwrites x1s, flies across MFMA
        asm volatile("" ::: "memory");

        const char* buf = s_x2 + (ck & 1) * BUFSZ;
        #pragma unroll
        for (int gy = 0; gy < 4; ++gy) {
            #pragma unroll
            for (int gx = 0; gx < 4; ++gx) {
                const int p2y = wy * 8 + gy * 4 + dy;
                const int p2x = wx * 8 + gx * 4 + dx;
                union { short8 s8; unsigned u4[4]; } bfu;
                const bool act = (quad < 2) && ((pmask >> (gy * 4 + gx)) & 1u);
                if (act) {
                    const float* fb = (const float*)(buf + (p2x >> 2) * 6144
                                      + quad * 3072 + p2y * 16 + (p2x & 3) * 4);
                    #pragma unroll
                    for (int t = 0; t < 4; ++t)
                        bfu.u4[t] = packbf(fb[(2 * t) * 96], fb[(2 * t + 1) * 96]);
                } else {
                    bfu.u4[0] = bfu.u4[1] = bfu.u4[2] = bfu.u4[3] = 0u;
                }
                const short8 Bf = bfu.s8;
                #pragma unroll
                for (int mty = 0; mty < 2; ++mty) {
                    const int oyi = gy - mty;
                    if (oyi < 0 || oyi > 2) continue;
                    #pragma unroll
                    for (int mtx = 0; mtx < 2; ++mtx) {
                        const int oxi = gx - mtx;
                        if (oxi < 0 || oxi > 2) continue;
                        acc[mty][mtx][oyi * 3 + oxi] =
                            __builtin_amdgcn_mfma_f32_16x16x32_bf16(
                                A[mty][mtx], Bf, acc[mty][mtx][oyi * 3 + oxi], 0, 0, 0);
                    }
                }
            }
        }
    }

    // ---- epilogue: band extraction -> LDS slices -> coalesced nt writes ----
    // 81 = 3 slices x 27 idx channels; slice buffer = 27*16*16*4 = 27648 B.
    const float scale = 1.0f / 81.0f;
    const int nq = (lane >> 2) & 3;
    const int nx = lane & 3;
    float* s_out = (float*)s_x2;
    for (int sl = 0; sl < 3; ++sl) {
        const int lo = 27 * sl;
        __syncthreads();         // prior LDS use (frag reads / prev slice) done
        #pragma unroll
        for (int mty = 0; mty < 2; ++mty) {
            #pragma unroll
            for (int mtx = 0; mtx < 2; ++mtx) {
                const int oyl = wy * 8 + mty * 4 + quad;    // row within tile
                const int oxb = wx * 8 + mtx * 4;           // col base within tile
                #pragma unroll
                for (int oyi = 0; oyi < 3; ++oyi) {
                    const int ip = quad - nq - 4 * (oyi - 1);
                    if ((unsigned)(ip + SR) > 8u) continue;
                    #pragma unroll
                    for (int oxi = 0; oxi < 3; ++oxi) {
                        #pragma unroll
                        for (int reg = 0; reg < 4; ++reg) {
                            const int jp = reg - nx - 4 * (oxi - 1);
                            if ((unsigned)(jp + SR) > 8u) continue;
                            int idx = 9 * ip + jp;
                            if (idx < 0) idx += NDISP;
                            idx -= lo;
                            if ((unsigned)idx < 27u)
                                s_out[(idx << 8) + (oyl << 4) + oxb + reg] =
                                    acc[mty][mtx][oyi * 3 + oxi][reg] * scale;
                        }
                    }
                }
            }
        }
        __syncthreads();
        // cooperative full-line nt writes: 27*16 rows of 64B; 4 lanes per row.
        for (int k = tid; k < 27 * 64; k += 256) {
            const int idx_l = k >> 6;
            const int rem   = k & 63;
            const int row   = rem >> 2;
            const int c4    = rem & 3;
            float4v v = *(const float4v*)(s_out + 4 * k);
            __builtin_nontemporal_store(v,
                (float4v*)(out + ((size_t)(bz * NDISP + lo + idx_l) * HH + y0 + row) * WW
                           + x0 + (c4 << 2)));
        }
    }
}

extern "C" void kernel_launch(void* const* d_in, const int* in_sizes, int n_in,
                              void* d_out, int out_size, void* d_ws, size_t ws_size,
                              hipStream_t stream) {
    const float* x1 = (const float*)d_in[0];
    const float* x2 = (const float*)d_in[1];
    float* out = (float*)d_out;
    (void)in_sizes; (void)n_in; (void)out_size; (void)d_ws; (void)ws_size;

    dim3 grid(WW / TILE, HH / TILE, BB);   // (16, 8, 8) = 1024 blocks
    costvol_kernel<<<grid, 256, 0, stream>>>(x1, x2, out);
}

// Round 7
// 508.144 us; speedup vs baseline: 2.1054x; 1.0295x over previous
//
#include <hip/hip_runtime.h>

// CostVolumeLayer: out[b, idx(i,j), y, x] = (1/81) * sum_c x1[b,c,y,x] * x2[b,c,y-i,x-j]
// i,j in [-4,4], idx = (9i+j) mod 81.  x1,x2: (8,192,128,256) fp32; out: (8,81,128,256) fp32.
//
// Round 9: round-8's global_load_lds broke the register-concurrency cap
// (430 -> 254us, BW now 16% => memory no longer limits). Now frag-build
// instruction-bound: K=16 data on a K=32 MFMA left half the lanes idle doing
// 8 ds_read_b32 + 4 packs per position. This round:
//  - NATIVE K=16 MFMA (v_mfma_f32_16x16x16_bf16 via the _1k builtin spelling,
//    __has_builtin-guarded with fallback to zeroed-K32): all 4 quads carry
//    4 ch each -> per position 4 reads + 2 packs spread over 64 lanes
//    (halves frag-build instruction count); x1 loads halve to 16/chunk.
//  - channel stride padded 384 -> 400 B (100 dw === 4 mod 32): 4-quad reads
//    are 2-way banked (free) instead of 4-way. Pad granules are skipped via
//    per-lane DMA masking (never written, never read). Buffer 38400 B x2.

#define SR     4
#define NDISP  81
#define CH     192
#define HH     128
#define WW     256
#define BB     8
#define TILE   16
#define REGN   24          // TILE + 2*SR
#define KC     16          // channels per chunk (fp32 in LDS)
#define NCHUNK 12          // 192/16
#define HWSZ   (HH * WW)   // 32768, fits int
#define CSTRIDE 400        // bytes per channel row-group in LDS (384 data + 16 pad)
#define VXSTRIDE 6400      // 16 ch * 400
#define BUFSZ  (6 * VXSTRIDE)   // 38400 B per buffer
#define NDMA   10          // global_load_lds instructions per wave per chunk

typedef __attribute__((ext_vector_type(8))) short  short8;
typedef __attribute__((ext_vector_type(4))) short  short4v;
typedef __attribute__((ext_vector_type(4))) float  float4v;

#if __has_builtin(__builtin_amdgcn_cvt_pk_bf16_f32)
typedef __attribute__((ext_vector_type(2))) __bf16 bf16x2;
__device__ __forceinline__ unsigned packbf(float a, float b) {
    union { bf16x2 v; unsigned u; } c;
    c.v = __builtin_amdgcn_cvt_pk_bf16_f32(a, b);   // lo=a, hi=b
    return c.u;
}
#else
__device__ __forceinline__ unsigned short f2bf(float f) {
    union { float f; unsigned u; } v; v.f = f;
    unsigned r = v.u + 0x7FFFu + ((v.u >> 16) & 1u);
    return (unsigned short)(r >> 16);
}
__device__ __forceinline__ unsigned packbf(float a, float b) {
    return (unsigned)f2bf(a) | ((unsigned)f2bf(b) << 16);
}
#endif

#if __has_builtin(__builtin_amdgcn_mfma_f32_16x16x16bf16_1k)
#define HAS_K16 1
#define VMCNT_KEEP "s_waitcnt vmcnt(16)\n\ts_barrier"   // keep the 16 x1 loads in flight
#else
#define HAS_K16 0
#define VMCNT_KEEP "s_waitcnt vmcnt(32)\n\ts_barrier"   // fallback: 32 x1 loads
#endif

typedef __attribute__((address_space(1))) void gvoid;
typedef __attribute__((address_space(3))) void lvoid;
__device__ __forceinline__ void gl_lds16(const void* g, void* l) {
    __builtin_amdgcn_global_load_lds((gvoid*)g, (lvoid*)l, 16, 0, 0);
}

__global__ __launch_bounds__(256, 2)
void costvol_kernel(const float* __restrict__ x1, const float* __restrict__ x2,
                    float* __restrict__ out) {
    __shared__ __align__(16) char s_x2[2 * BUFSZ];   // 76800 B (fp32 double buffer)

    const int tid = threadIdx.x;

    // ---- XCD-aware bijective swizzle ----
    const int flat = blockIdx.x + (blockIdx.y << 4) + (blockIdx.z << 7);
    const int swz  = ((flat & 7) << 7) + (flat >> 3);
    const int x0 = (swz & 15) * TILE;
    const int y0 = ((swz >> 4) & 7) * TILE;
    const int bz = swz >> 7;

    const int lane = tid & 63;
    const int wv   = tid >> 6;
    const int wy   = wv >> 1, wx = wv & 1;     // wave quadrant (8x8 px)
    const int quad = lane >> 4;                // K-group
    const int dy   = (lane & 15) >> 2;
    const int dx   = lane & 3;

    const float* x1b = x1 + (size_t)bz * CH * HWSZ;
    const float* x2b = x2 + (size_t)bz * CH * HWSZ;

    // ---- x2 DMA metadata: granule u = wv*640 + i*64 + lane, 16B each ----
    // u = vx*400 + c*25 + ry  (ry==24 is the pad slot; u>=2400 is tail pad)
    // LDS byte u*16 = vx*6400 + c*400 + ry*16  -> addr(c,y,x) matches reads.
    int g_off[NDMA];
    unsigned gmask = 0;
    #pragma unroll
    for (int i = 0; i < NDMA; ++i) {
        int u  = wv * 640 + i * 64 + lane;
        int vx = u / 400, r = u - vx * 400;
        int c  = r / 25,  ry = r - c * 25;
        bool valid = (u < 2400) && (ry != 24);
        int gy = y0 - SR + ry, gx = x0 - SR + 4 * vx;
        int gyc = min(max(gy, 0), HH - 1);      // clamped, always-valid 16B-aligned
        int gxc = min(max(gx, 0), WW - 4);      // (OOB zeroed via pmask at frag build)
        g_off[i] = c * HWSZ + gyc * WW + gxc;
        gmask |= (unsigned)valid << i;
    }
    // per-pixel validity for the 16 (gy,gx) fragment positions
    unsigned pmask = 0;
    #pragma unroll
    for (int gy = 0; gy < 4; ++gy)
        #pragma unroll
        for (int gx = 0; gx < 4; ++gx) {
            int p2y = wy * 8 + gy * 4 + dy, p2x = wx * 8 + gx * 4 + dx;
            bool ok = ((unsigned)(y0 - SR + p2y) < (unsigned)HH) &&
                      ((unsigned)(x0 - SR + p2x) < (unsigned)WW);
            pmask |= (unsigned)ok << (gy * 4 + gx);
        }
    // x1 pixel offsets for the 4 A-fragments (lane-fixed)
    int pixoff[2][2];
    #pragma unroll
    for (int mty = 0; mty < 2; ++mty)
        #pragma unroll
        for (int mtx = 0; mtx < 2; ++mtx)
            pixoff[mty][mtx] = (y0 + wy * 8 + mty * 4 + dy) * WW
                             + (x0 + wx * 8 + mtx * 4 + dx);

    float4v acc[2][2][9];
    #pragma unroll
    for (int a = 0; a < 2; ++a)
        #pragma unroll
        for (int b = 0; b < 2; ++b)
            #pragma unroll
            for (int o = 0; o < 9; ++o)
                acc[a][b][o] = (float4v){0.f, 0.f, 0.f, 0.f};

#if HAS_K16
    float   x1s[2][2][4];      // 4 ch per quad (K=16 native)
    short4v A[2][2];
#else
    float   x1s[2][2][8];      // 8 ch per quad, quads 0-1 (K=32 zero-padded)
    short8  A[2][2];
#endif

    auto issue_dma = [&](int ck, int bufsel) {
        const float* p2 = x2b + (size_t)(ck * KC) * HWSZ;
        char* lbase = s_x2 + bufsel * BUFSZ + wv * (NDMA * 1024);
        #pragma unroll
        for (int i = 0; i < NDMA; ++i)
            if ((gmask >> i) & 1u)
                gl_lds16((const void*)(p2 + g_off[i]), (void*)(lbase + i * 1024));
    };
    auto issue_x1 = [&](int ck) {
#if HAS_K16
        const float* p1 = x1b + (size_t)(ck * KC + quad * 4) * HWSZ;
        #pragma unroll
        for (int mty = 0; mty < 2; ++mty)
            #pragma unroll
            for (int mtx = 0; mtx < 2; ++mtx)
                #pragma unroll
                for (int j = 0; j < 4; ++j)
                    x1s[mty][mtx][j] = p1[(size_t)j * HWSZ + pixoff[mty][mtx]];
#else
        if (quad < 2) {
            const float* p1 = x1b + (size_t)(ck * KC + quad * 8) * HWSZ;
            #pragma unroll
            for (int mty = 0; mty < 2; ++mty)
                #pragma unroll
                for (int mtx = 0; mtx < 2; ++mtx)
                    #pragma unroll
                    for (int j = 0; j < 8; ++j)
                        x1s[mty][mtx][j] = p1[(size_t)j * HWSZ + pixoff[mty][mtx]];
        }
#endif
    };
    auto build_A = [&]() {
        #pragma unroll
        for (int mty = 0; mty < 2; ++mty)
            #pragma unroll
            for (int mtx = 0; mtx < 2; ++mtx) {
#if HAS_K16
                union { short4v s4; unsigned u2[2]; } af;
                #pragma unroll
                for (int t = 0; t < 2; ++t)
                    af.u2[t] = packbf(x1s[mty][mtx][2 * t], x1s[mty][mtx][2 * t + 1]);
                A[mty][mtx] = af.s4;
#else
                union { short8 s8; unsigned u4[4]; } af;
                #pragma unroll
                for (int t = 0; t < 4; ++t)
                    af.u4[t] = (quad < 2)
                        ? packbf(x1s[mty][mtx][2 * t], x1s[mty][mtx][2 * t + 1])
                        : 0u;
                A[mty][mtx] = af.s8;
#endif
            }
    };

    // Prologue (issue order pins the vmcnt arithmetic: DMA first, then x1).
    issue_dma(0, 0);
    asm volatile("" ::: "memory");
    issue_x1(0);
    asm volatile("" ::: "memory");

    for (int ck = 0; ck < NCHUNK; ++ck) {
        // Retire my DMA(ck) (x1(ck) stays in flight); barrier: all waves' DMA(ck)
        // landed and all are past MFMA(ck-1) -> read buf[ck&1], overwrite other.
        asm volatile(VMCNT_KEEP ::: "memory");
        if (ck + 1 < NCHUNK) issue_dma(ck + 1, (ck + 1) & 1);
        asm volatile("" ::: "memory");
        build_A();                             // consumes x1s(ck)
        if (ck + 1 < NCHUNK) issue_x1(ck + 1); // flies across the MFMA phase
        asm volatile("" ::: "memory");

        const char* buf = s_x2 + (ck & 1) * BUFSZ;
        #pragma unroll
        for (int gy = 0; gy < 4; ++gy) {
            #pragma unroll
            for (int gx = 0; gx < 4; ++gx) {
                const int p2y = wy * 8 + gy * 4 + dy;
                const int p2x = wx * 8 + gx * 4 + dx;
                const bool okp = (pmask >> (gy * 4 + gx)) & 1u;
                const float* fb = (const float*)(buf + (p2x >> 2) * VXSTRIDE
                                   + p2y * 16 + (p2x & 3) * 4);
#if HAS_K16
                union { short4v s4; unsigned u2[2]; } bfu;
                if (okp) {
                    const float* fq = fb + quad * 400;     // quad*4 ch * 100 floats
                    #pragma unroll
                    for (int t = 0; t < 2; ++t)
                        bfu.u2[t] = packbf(fq[(2 * t) * 100], fq[(2 * t + 1) * 100]);
                } else {
                    bfu.u2[0] = bfu.u2[1] = 0u;
                }
                const short4v Bf = bfu.s4;
#else
                union { short8 s8; unsigned u4[4]; } bfu;
                if ((quad < 2) && okp) {
                    const float* fq = fb + quad * 800;     // quad*8 ch * 100 floats
                    #pragma unroll
                    for (int t = 0; t < 4; ++t)
                        bfu.u4[t] = packbf(fq[(2 * t) * 100], fq[(2 * t + 1) * 100]);
                } else {
                    bfu.u4[0] = bfu.u4[1] = bfu.u4[2] = bfu.u4[3] = 0u;
                }
                const short8 Bf = bfu.s8;
#endif
                #pragma unroll
                for (int mty = 0; mty < 2; ++mty) {
                    const int oyi = gy - mty;
                    if (oyi < 0 || oyi > 2) continue;
                    #pragma unroll
                    for (int mtx = 0; mtx < 2; ++mtx) {
                        const int oxi = gx - mtx;
                        if (oxi < 0 || oxi > 2) continue;
#if HAS_K16
                        acc[mty][mtx][oyi * 3 + oxi] =
                            __builtin_amdgcn_mfma_f32_16x16x16bf16_1k(
                                A[mty][mtx], Bf, acc[mty][mtx][oyi * 3 + oxi], 0, 0, 0);
#else
                        acc[mty][mtx][oyi * 3 + oxi] =
                            __builtin_amdgcn_mfma_f32_16x16x32_bf16(
                                A[mty][mtx], Bf, acc[mty][mtx][oyi * 3 + oxi], 0, 0, 0);
#endif
                    }
                }
            }
        }
    }

    // ---- epilogue: band extraction -> LDS slices -> coalesced nt writes ----
    const float scale = 1.0f / 81.0f;
    const int nq = (lane >> 2) & 3;
    const int nx = lane & 3;
    float* s_out = (float*)s_x2;
    for (int sl = 0; sl < 3; ++sl) {
        const int lo = 27 * sl;
        __syncthreads();
        #pragma unroll
        for (int mty = 0; mty < 2; ++mty) {
            #pragma unroll
            for (int mtx = 0; mtx < 2; ++mtx) {
                const int oyl = wy * 8 + mty * 4 + quad;
                const int oxb = wx * 8 + mtx * 4;
                #pragma unroll
                for (int oyi = 0; oyi < 3; ++oyi) {
                    const int ip = quad - nq - 4 * (oyi - 1);
                    if ((unsigned)(ip + SR) > 8u) continue;
                    #pragma unroll
                    for (int oxi = 0; oxi < 3; ++oxi) {
                        #pragma unroll
                        for (int reg = 0; reg < 4; ++reg) {
                            const int jp = reg - nx - 4 * (oxi - 1);
                            if ((unsigned)(jp + SR) > 8u) continue;
                            int idx = 9 * ip + jp;
                            if (idx < 0) idx += NDISP;
                            idx -= lo;
                            if ((unsigned)idx < 27u)
                                s_out[(idx << 8) + (oyl << 4) + oxb + reg] =
                                    acc[mty][mtx][oyi * 3 + oxi][reg] * scale;
                        }
                    }
                }
            }
        }
        __syncthreads();
        for (int k = tid; k < 27 * 64; k += 256) {
            const int idx_l = k >> 6;
            const int rem   = k & 63;
            const int row   = rem >> 2;
            const int c4    = rem & 3;
            float4v v = *(const float4v*)(s_out + 4 * k);
            __builtin_nontemporal_store(v,
                (float4v*)(out + ((size_t)(bz * NDISP + lo + idx_l) * HH + y0 + row) * WW
                           + x0 + (c4 << 2)));
        }
    }
}

extern "C" void kernel_launch(void* const* d_in, const int* in_sizes, int n_in,
                              void* d_out, int out_size, void* d_ws, size_t ws_size,
                              hipStream_t stream) {
    const float* x1 = (const float*)d_in[0];
    const float* x2 = (const float*)d_in[1];
    float* out = (float*)d_out;
    (void)in_sizes; (void)n_in; (void)out_size; (void)d_ws; (void)ws_size;

    dim3 grid(WW / TILE, HH / TILE, BB);   // (16, 8, 8) = 1024 blocks
    costvol_kernel<<<grid, 256, 0, stream>>>(x1, x2, out);
}

// Round 8
// 479.259 us; speedup vs baseline: 2.2322x; 1.0603x over previous
//
#include <hip/hip_runtime.h>

// CostVolumeLayer: out[b, idx(i,j), y, x] = (1/81) * sum_c x1[b,c,y,x] * x2[b,c,y-i,x-j]
// i,j in [-4,4], idx = (9i+j) mod 81.  x1,x2: (8,192,128,256) fp32; out: (8,81,128,256) fp32.
//
// Round 10: round-9 (K16 MFMA) halved VALU work but dur 254->240 only => not
// instruction-bound. Budget analysis: ~12k cy/CU/chunk vs ~600 cy of visible
// work; the gap is VMEM TRANSACTIONS: the DMA's lane->granule map scattered 64
// lanes across 64 cache lines per instruction (2560 line-accesses/block/chunk).
// Fix: ROW-MAJOR COALESCED granule order (c,ry,vx): 6 consecutive lanes cover
// one 96B row contiguously -> ~21 lines/instr (3.2x fewer transactions).
// The implied LDS layout [c][ry][vx] (+1 pad granule per channel, c-stride
// 2320B === 16 mod 32 dw) also makes B-frag reads 2-way banked (free) and lets
// all 64 B-position ds_reads share ONE address register (offsets become
// compile-time immediates). x1 / K16 MFMA / pipeline / epilogue unchanged.

#define SR     4
#define NDISP  81
#define CH     192
#define HH     128
#define WW     256
#define BB     8
#define TILE   16
#define REGN   24          // TILE + 2*SR
#define KC     16          // channels per chunk (fp32 in LDS)
#define NCHUNK 12          // 192/16
#define HWSZ   (HH * WW)   // 32768, fits int
#define CSTRB  2320        // LDS bytes per channel: 145 granules (144 data + 1 pad)
#define BUFSZ  (KC * CSTRB)     // 37120 B per buffer
#define WVGRAN 580         // granules per wave per chunk (16*145/4)
#define NDMA   10          // ceil(580/64) DMA instructions per wave

typedef __attribute__((ext_vector_type(8))) short  short8;
typedef __attribute__((ext_vector_type(4))) short  short4v;
typedef __attribute__((ext_vector_type(4))) float  float4v;

#if __has_builtin(__builtin_amdgcn_cvt_pk_bf16_f32)
typedef __attribute__((ext_vector_type(2))) __bf16 bf16x2;
__device__ __forceinline__ unsigned packbf(float a, float b) {
    union { bf16x2 v; unsigned u; } c;
    c.v = __builtin_amdgcn_cvt_pk_bf16_f32(a, b);   // lo=a, hi=b
    return c.u;
}
#else
__device__ __forceinline__ unsigned short f2bf(float f) {
    union { float f; unsigned u; } v; v.f = f;
    unsigned r = v.u + 0x7FFFu + ((v.u >> 16) & 1u);
    return (unsigned short)(r >> 16);
}
__device__ __forceinline__ unsigned packbf(float a, float b) {
    return (unsigned)f2bf(a) | ((unsigned)f2bf(b) << 16);
}
#endif

#if __has_builtin(__builtin_amdgcn_mfma_f32_16x16x16bf16_1k)
#define HAS_K16 1
#define VMCNT_KEEP "s_waitcnt vmcnt(16)\n\ts_barrier"   // drain DMAs, keep 16 x1 loads
#else
#define HAS_K16 0
#define VMCNT_KEEP "s_waitcnt vmcnt(32)\n\ts_barrier"   // fallback: 32 x1 loads
#endif

typedef __attribute__((address_space(1))) void gvoid;
typedef __attribute__((address_space(3))) void lvoid;
__device__ __forceinline__ void gl_lds16(const void* g, void* l) {
    __builtin_amdgcn_global_load_lds((gvoid*)g, (lvoid*)l, 16, 0, 0);
}

__global__ __launch_bounds__(256, 2)
void costvol_kernel(const float* __restrict__ x1, const float* __restrict__ x2,
                    float* __restrict__ out) {
    __shared__ __align__(16) char s_x2[2 * BUFSZ];   // 74240 B (fp32 double buffer)

    const int tid = threadIdx.x;

    // ---- XCD-aware bijective swizzle ----
    const int flat = blockIdx.x + (blockIdx.y << 4) + (blockIdx.z << 7);
    const int swz  = ((flat & 7) << 7) + (flat >> 3);
    const int x0 = (swz & 15) * TILE;
    const int y0 = ((swz >> 4) & 7) * TILE;
    const int bz = swz >> 7;

    const int lane = tid & 63;
    const int wv   = tid >> 6;
    const int wy   = wv >> 1, wx = wv & 1;     // wave quadrant (8x8 px)
    const int quad = lane >> 4;                // K-group
    const int dy   = (lane & 15) >> 2;
    const int dx   = lane & 3;

    const float* x1b = x1 + (size_t)bz * CH * HWSZ;
    const float* x2b = x2 + (size_t)bz * CH * HWSZ;

    // ---- x2 DMA metadata: granule g = wv*580 + i*64 + lane ----
    // g = c*145 + ry*6 + vx (r==144 is the pad slot). Consecutive lanes are
    // CONTIGUOUS in global (16B steps within a 96B row) -> coalesced bursts.
    // LDS byte = g*16  ==> addr(c,y,x) = c*2320 + y*96 + x*4.
    int g_off[NDMA];
    unsigned gmask = 0;
    #pragma unroll
    for (int i = 0; i < NDMA; ++i) {
        int t = i * 64 + lane;                 // within-wave granule index
        int g = wv * WVGRAN + t;
        int c = g / 145, r = g - c * 145;
        int ry = r / 6,  vx = r - ry * 6;
        bool valid = (t < WVGRAN) && (r != 144);
        int gy = y0 - SR + ry, gx = x0 - SR + 4 * vx;
        int gyc = min(max(gy, 0), HH - 1);     // clamped, always-valid 16B-aligned
        int gxc = min(max(gx, 0), WW - 4);     // (OOB zeroed via pmask at frag build)
        g_off[i] = valid ? (c * HWSZ + gyc * WW + gxc) : 0;
        gmask |= (unsigned)valid << i;
    }
    // per-pixel validity for the 16 (gy,gx) fragment positions
    unsigned pmask = 0;
    #pragma unroll
    for (int gy = 0; gy < 4; ++gy)
        #pragma unroll
        for (int gx = 0; gx < 4; ++gx) {
            int p2y = wy * 8 + gy * 4 + dy, p2x = wx * 8 + gx * 4 + dx;
            bool ok = ((unsigned)(y0 - SR + p2y) < (unsigned)HH) &&
                      ((unsigned)(x0 - SR + p2x) < (unsigned)WW);
            pmask |= (unsigned)ok << (gy * 4 + gx);
        }
    // x1 pixel offsets for the 4 A-fragments (lane-fixed)
    int pixoff[2][2];
    #pragma unroll
    for (int mty = 0; mty < 2; ++mty)
        #pragma unroll
        for (int mtx = 0; mtx < 2; ++mtx)
            pixoff[mty][mtx] = (y0 + wy * 8 + mty * 4 + dy) * WW
                             + (x0 + wx * 8 + mtx * 4 + dx);

    // per-lane LDS base for B-frag reads: all 64 position/channel reads are
    // compile-time offsets (gy*384 + gx*16 + j*2320) from this one register.
#if HAS_K16
    const int bb_off = quad * (4 * CSTRB) + (wy * 8 + dy) * 96 + (wx * 8 + dx) * 4;
#else
    const int bb_off = quad * (8 * CSTRB) + (wy * 8 + dy) * 96 + (wx * 8 + dx) * 4;
#endif

    float4v acc[2][2][9];
    #pragma unroll
    for (int a = 0; a < 2; ++a)
        #pragma unroll
        for (int b = 0; b < 2; ++b)
            #pragma unroll
            for (int o = 0; o < 9; ++o)
                acc[a][b][o] = (float4v){0.f, 0.f, 0.f, 0.f};

#if HAS_K16
    float   x1s[2][2][4];      // 4 ch per quad (K=16 native)
    short4v A[2][2];
#else
    float   x1s[2][2][8];      // 8 ch per quad, quads 0-1 (K=32 zero-padded)
    short8  A[2][2];
#endif

    auto issue_dma = [&](int ck, int bufsel) {
        const float* p2 = x2b + (size_t)(ck * KC) * HWSZ;
        char* lbase = s_x2 + bufsel * BUFSZ + wv * (WVGRAN * 16);
        #pragma unroll
        for (int i = 0; i < NDMA; ++i)
            if ((gmask >> i) & 1u)
                gl_lds16((const void*)(p2 + g_off[i]), (void*)(lbase + i * 1024));
    };
    auto issue_x1 = [&](int ck) {
#if HAS_K16
        const float* p1 = x1b + (size_t)(ck * KC + quad * 4) * HWSZ;
        #pragma unroll
        for (int mty = 0; mty < 2; ++mty)
            #pragma unroll
            for (int mtx = 0; mtx < 2; ++mtx)
                #pragma unroll
                for (int j = 0; j < 4; ++j)
                    x1s[mty][mtx][j] = p1[(size_t)j * HWSZ + pixoff[mty][mtx]];
#else
        if (quad < 2) {
            const float* p1 = x1b + (size_t)(ck * KC + quad * 8) * HWSZ;
            #pragma unroll
            for (int mty = 0; mty < 2; ++mty)
                #pragma unroll
                for (int mtx = 0; mtx < 2; ++mtx)
                    #pragma unroll
                    for (int j = 0; j < 8; ++j)
                        x1s[mty][mtx][j] = p1[(size_t)j * HWSZ + pixoff[mty][mtx]];
        }
#endif
    };
    auto build_A = [&]() {
        #pragma unroll
        for (int mty = 0; mty < 2; ++mty)
            #pragma unroll
            for (int mtx = 0; mtx < 2; ++mtx) {
#if HAS_K16
                union { short4v s4; unsigned u2[2]; } af;
                #pragma unroll
                for (int t = 0; t < 2; ++t)
                    af.u2[t] = packbf(x1s[mty][mtx][2 * t], x1s[mty][mtx][2 * t + 1]);
                A[mty][mtx] = af.s4;
#else
                union { short8 s8; unsigned u4[4]; } af;
                #pragma unroll
                for (int t = 0; t < 4; ++t)
                    af.u4[t] = (quad < 2)
                        ? packbf(x1s[mty][mtx][2 * t], x1s[mty][mtx][2 * t + 1])
                        : 0u;
                A[mty][mtx] = af.s8;
#endif
            }
    };

    // Prologue (issue order pins the vmcnt arithmetic: DMA first, then x1).
    issue_dma(0, 0);
    asm volatile("" ::: "memory");
    issue_x1(0);
    asm volatile("" ::: "memory");

    for (int ck = 0; ck < NCHUNK; ++ck) {
        // Retire my DMA(ck) (x1(ck) stays in flight); barrier: all waves' DMA(ck)
        // landed and all are past MFMA(ck-1) -> read buf[ck&1], overwrite other.
        asm volatile(VMCNT_KEEP ::: "memory");
        if (ck + 1 < NCHUNK) issue_dma(ck + 1, (ck + 1) & 1);
        asm volatile("" ::: "memory");
        build_A();                             // consumes x1s(ck)
        if (ck + 1 < NCHUNK) issue_x1(ck + 1); // flies across the MFMA phase
        asm volatile("" ::: "memory");

        const char* buf = s_x2 + (ck & 1) * BUFSZ;
        #pragma unroll
        for (int gy = 0; gy < 4; ++gy) {
            #pragma unroll
            for (int gx = 0; gx < 4; ++gx) {
                const bool okp = (pmask >> (gy * 4 + gx)) & 1u;
                const float* fq = (const float*)(buf + bb_off + gy * 384 + gx * 16);
#if HAS_K16
                union { short4v s4; unsigned u2[2]; } bfu;
                if (okp) {
                    #pragma unroll
                    for (int t = 0; t < 2; ++t)
                        bfu.u2[t] = packbf(fq[(2 * t) * 580], fq[(2 * t + 1) * 580]);
                } else {
                    bfu.u2[0] = bfu.u2[1] = 0u;
                }
                const short4v Bf = bfu.s4;
#else
                union { short8 s8; unsigned u4[4]; } bfu;
                if ((quad < 2) && okp) {
                    #pragma unroll
                    for (int t = 0; t < 4; ++t)
                        bfu.u4[t] = packbf(fq[(2 * t) * 580], fq[(2 * t + 1) * 580]);
                } else {
                    bfu.u4[0] = bfu.u4[1] = bfu.u4[2] = bfu.u4[3] = 0u;
                }
                const short8 Bf = bfu.s8;
#endif
                #pragma unroll
                for (int mty = 0; mty < 2; ++mty) {
                    const int oyi = gy - mty;
                    if (oyi < 0 || oyi > 2) continue;
                    #pragma unroll
                    for (int mtx = 0; mtx < 2; ++mtx) {
                        const int oxi = gx - mtx;
                        if (oxi < 0 || oxi > 2) continue;
#if HAS_K16
                        acc[mty][mtx][oyi * 3 + oxi] =
                            __builtin_amdgcn_mfma_f32_16x16x16bf16_1k(
                                A[mty][mtx], Bf, acc[mty][mtx][oyi * 3 + oxi], 0, 0, 0);
#else
                        acc[mty][mtx][oyi * 3 + oxi] =
                            __builtin_amdgcn_mfma_f32_16x16x32_bf16(
                                A[mty][mtx], Bf, acc[mty][mtx][oyi * 3 + oxi], 0, 0, 0);
#endif
                    }
                }
            }
        }
    }

    // ---- epilogue: band extraction -> LDS slices -> coalesced nt writes ----
    const float scale = 1.0f / 81.0f;
    const int nq = (lane >> 2) & 3;
    const int nx = lane & 3;
    float* s_out = (float*)s_x2;
    for (int sl = 0; sl < 3; ++sl) {
        const int lo = 27 * sl;
        __syncthreads();
        #pragma unroll
        for (int mty = 0; mty < 2; ++mty) {
            #pragma unroll
            for (int mtx = 0; mtx < 2; ++mtx) {
                const int oyl = wy * 8 + mty * 4 + quad;
                const int oxb = wx * 8 + mtx * 4;
                #pragma unroll
                for (int oyi = 0; oyi < 3; ++oyi) {
                    const int ip = quad - nq - 4 * (oyi - 1);
                    if ((unsigned)(ip + SR) > 8u) continue;
                    #pragma unroll
                    for (int oxi = 0; oxi < 3; ++oxi) {
                        #pragma unroll
                        for (int reg = 0; reg < 4; ++reg) {
                            const int jp = reg - nx - 4 * (oxi - 1);
                            if ((unsigned)(jp + SR) > 8u) continue;
                            int idx = 9 * ip + jp;
                            if (idx < 0) idx += NDISP;
                            idx -= lo;
                            if ((unsigned)idx < 27u)
                                s_out[(idx << 8) + (oyl << 4) + oxb + reg] =
                                    acc[mty][mtx][oyi * 3 + oxi][reg] * scale;
                        }
                    }
                }
            }
        }
        __syncthreads();
        for (int k = tid; k < 27 * 64; k += 256) {
            const int idx_l = k >> 6;
            const int rem   = k & 63;
            const int row   = rem >> 2;
            const int c4    = rem & 3;
            float4v v = *(const float4v*)(s_out + 4 * k);
            __builtin_nontemporal_store(v,
                (float4v*)(out + ((size_t)(bz * NDISP + lo + idx_l) * HH + y0 + row) * WW
                           + x0 + (c4 << 2)));
        }
    }
}

extern "C" void kernel_launch(void* const* d_in, const int* in_sizes, int n_in,
                              void* d_out, int out_size, void* d_ws, size_t ws_size,
                              hipStream_t stream) {
    const float* x1 = (const float*)d_in[0];
    const float* x2 = (const float*)d_in[1];
    float* out = (float*)d_out;
    (void)in_sizes; (void)n_in; (void)out_size; (void)d_ws; (void)ws_size;

    dim3 grid(WW / TILE, HH / TILE, BB);   // (16, 8, 8) = 1024 blocks
    costvol_kernel<<<grid, 256, 0, stream>>>(x1, x2, out);
}